// Round 9
// baseline (462.205 us; speedup 1.0000x reference)
//
#include <hip/hip_runtime.h>
#include <hip/hip_bf16.h>

// Transformer block for MI355X. Round 9: software-pipelined attention k-loop
// (double-buffered Ks/VT; next-tile K-DMA + V-register loads issued before
// current-tile compute -> HBM latency overlapped; was fully exposed at
// 1 block/CU). GEMMs/rmsnorm/wprep unchanged from round 8. Symbols _r9.

typedef __hip_bfloat16 bf16;
typedef __attribute__((ext_vector_type(8))) short short8;   // 8 bf16 = 4 VGPRs
typedef __attribute__((ext_vector_type(4))) float floatx4;  // MFMA C/D frag

__device__ __forceinline__ float bits2f(unsigned short u) {
  union { unsigned int i; float f; } c; c.i = ((unsigned int)u) << 16; return c.f;
}
__device__ __forceinline__ unsigned short f2bits(float f) {
  bf16 b = __float2bfloat16(f);
  union { bf16 b; unsigned short u; } c; c.b = b; return c.u;
}

__device__ __forceinline__ void gld_lds16(const unsigned short* g, unsigned short* l) {
  __builtin_amdgcn_global_load_lds(
      (const __attribute__((address_space(1))) void*)g,
      (__attribute__((address_space(3))) void*)l, 16, 0, 0);
}

// ---------------- RMSNorm: f32 in, f32 gamma, bf16 out ----------------
__global__ __launch_bounds__(256) void rmsnorm_r9(const float* __restrict__ x,
                                                  const float* __restrict__ g,
                                                  unsigned short* __restrict__ out)
{
  const int row = blockIdx.x, tid = threadIdx.x;
  const size_t rb = (size_t)row * 1024;
  float4 xv = *(const float4*)(x + rb + tid * 4);
  float v[4] = {xv.x, xv.y, xv.z, xv.w};
  float s = v[0]*v[0] + v[1]*v[1] + v[2]*v[2] + v[3]*v[3];
  #pragma unroll
  for (int off = 32; off > 0; off >>= 1) s += __shfl_down(s, off, 64);
  __shared__ float part[4];
  if ((tid & 63) == 0) part[tid >> 6] = s;
  __syncthreads();
  const float tot = part[0] + part[1] + part[2] + part[3];
  const float sc = rsqrtf(tot * (1.0f / 1024.0f) + 1.1920929e-07f);
  float4 gv = *(const float4*)(g + tid * 4);
  ushort4 o4 = { f2bits(v[0] * sc * gv.x), f2bits(v[1] * sc * gv.y),
                 f2bits(v[2] * sc * gv.z), f2bits(v[3] * sc * gv.w) };
  *(ushort4*)(out + rb + tid * 4) = o4;
}

// ---------------- Weight prep: W f32 [K,N] -> WT bf16 [N,K] ----------------
__global__ __launch_bounds__(256) void wprep_r9(const float* __restrict__ in,
                                                unsigned short* __restrict__ out,
                                                int K, int N)
{
  __shared__ unsigned short tile[32][33];
  const int tid = threadIdx.x;
  const int k0 = blockIdx.y * 32, n0 = blockIdx.x * 32;
  const int tr = tid >> 3, tc4 = (tid & 7) * 4;
  float4 v = *(const float4*)(in + (size_t)(k0 + tr) * N + n0 + tc4);
  tile[tr][tc4 + 0] = f2bits(v.x);
  tile[tr][tc4 + 1] = f2bits(v.y);
  tile[tr][tc4 + 2] = f2bits(v.z);
  tile[tr][tc4 + 3] = f2bits(v.w);
  __syncthreads();
  ushort4 o = { tile[tc4 + 0][tr], tile[tc4 + 1][tr],
                tile[tc4 + 2][tr], tile[tc4 + 3][tr] };
  *(ushort4*)(out + (size_t)(n0 + tr) * K + k0 + tc4) = o;
}

// ---------------- MFMA GEMM (unchanged): C = A @ BT^T + bias ----------------
template<int EPI>
__global__ __launch_bounds__(256) void gemm_r9(
    const unsigned short* __restrict__ A,
    const unsigned short* __restrict__ BT,
    const float* __restrict__ bias,
    const float* __restrict__ resid,
    void* __restrict__ Cout,
    int M, int N, int K)
{
  __shared__ __align__(16) unsigned short As[128 * 32];
  __shared__ __align__(16) unsigned short Bs[128 * 32];
  const int tid = threadIdx.x;
  const int lane = tid & 63;
  const int wv = tid >> 6;
  const int m0 = blockIdx.y * 128, n0 = blockIdx.x * 128;
  const int wm = (wv >> 1) * 64, wn = (wv & 1) * 64;

  const int s0 = tid, s1 = tid + 256;
  const int r0 = s0 >> 2, kq0 = (s0 & 3) ^ ((r0 >> 1) & 3);
  const int r1 = s1 >> 2, kq1 = (s1 & 3) ^ ((r1 >> 1) & 3);
  const unsigned short* Ab = A  + (size_t)m0 * K;
  const unsigned short* Bb = BT + (size_t)n0 * K;
  const size_t ga0 = (size_t)r0 * K + kq0 * 8;
  const size_t ga1 = (size_t)r1 * K + kq1 * 8;

  floatx4 acc[4][4];
  #pragma unroll
  for (int i = 0; i < 4; ++i)
    #pragma unroll
    for (int j = 0; j < 4; ++j)
      acc[i][j] = (floatx4){0.f, 0.f, 0.f, 0.f};

  int aoff[4], boff[4];
  #pragma unroll
  for (int i = 0; i < 4; ++i) {
    int ra = wm + i * 16 + (lane & 15);
    aoff[i] = (ra * 4 + ((lane >> 4) ^ ((ra >> 1) & 3))) * 8;
    int rb = wn + i * 16 + (lane & 15);
    boff[i] = (rb * 4 + ((lane >> 4) ^ ((rb >> 1) & 3))) * 8;
  }

  for (int k0 = 0; k0 < K; k0 += 32) {
    __syncthreads();
    gld_lds16(Ab + ga0 + k0, As + s0 * 8);
    gld_lds16(Ab + ga1 + k0, As + s1 * 8);
    gld_lds16(Bb + ga0 + k0, Bs + s0 * 8);
    gld_lds16(Bb + ga1 + k0, Bs + s1 * 8);
    __syncthreads();

    short8 af[4], bfr[4];
    #pragma unroll
    for (int i = 0; i < 4; ++i) {
      af[i]  = *(const short8*)(As + aoff[i]);
      bfr[i] = *(const short8*)(Bs + boff[i]);
    }
    #pragma unroll
    for (int i = 0; i < 4; ++i)
      #pragma unroll
      for (int j = 0; j < 4; ++j)
        acc[i][j] = __builtin_amdgcn_mfma_f32_16x16x32_bf16(af[i], bfr[j], acc[i][j], 0, 0, 0);
  }

  #pragma unroll
  for (int i = 0; i < 4; ++i) {
    #pragma unroll
    for (int j = 0; j < 4; ++j) {
      const int rbase = m0 + wm + i * 16 + (lane >> 4) * 4;
      const int c = n0 + wn + j * 16 + (lane & 15);
      const float bia = bias[c];
      #pragma unroll
      for (int r = 0; r < 4; ++r) {
        float v = acc[i][j][r] + bia;
        const size_t idx = (size_t)(rbase + r) * N + c;
        if constexpr (EPI == 0) {
          ((unsigned short*)Cout)[idx] = f2bits(v);
        } else if constexpr (EPI == 1) {
          ((float*)Cout)[idx] = v + resid[idx];
        } else if constexpr (EPI == 2) {
          v = 0.5f * v * (1.0f + erff(v * 0.70710678118654752f));
          ((unsigned short*)Cout)[idx] = f2bits(v);
        } else {
          ((float*)Cout)[idx] = v + resid[idx];
        }
      }
    }
  }
}

// ---------------- MFMA flash attention: pair-per-block + pipelined k-loop ----------------
// Grid dim3(8,32): pass 0 -> qt=15-qt0 (heavy), pass 1 -> qt=qt0. 34 k-iters/block.
// Double-buffered Ks/VT: next tile's K-DMA and V global->VGPR loads issued
// BEFORE current-tile compute; first barrier drains (overlapped), ds_write VT,
// second barrier publishes.
__global__ __launch_bounds__(256) void attn_r9(const unsigned short* __restrict__ qkv,
                                               unsigned short* __restrict__ o)
{
  __shared__ __align__(16) unsigned short Qs[128 * 64];     // swizzled chunks
  __shared__ __align__(16) unsigned short Ks[2][64 * 64];   // swizzled chunks, dbuf
  __shared__ __align__(16) unsigned short VT[2][64 * 72];   // [d][tok], pad 72, dbuf
  __shared__ __align__(16) unsigned short Ps[128 * 72];     // [q][tok], wave-own rows
  __shared__ __align__(16) float stat_s[128];               // alpha / l (wave-own rows)

  const int tid = threadIdx.x, lane = tid & 63, wv = tid >> 6;
  const int quad = lane >> 4, l15 = lane & 15;
  const int qt0 = blockIdx.x, bh = blockIdx.y;
  const int b = bh >> 4, h = bh & 15;
  const size_t base = (size_t)b * 2048 * 3072;
  const int qcol = h * 64, kcol = 1024 + h * 64, vcol = 2048 + h * 64;

  // staging index precompute (K: 2 slots/thread; V: tok pair x 8 dims)
  const int ks0 = tid,        kr0 = ks0 >> 3, kc0 = (ks0 & 7) ^ (kr0 & 7);
  const int ks1 = tid + 256,  kr1 = ks1 >> 3, kc1 = (ks1 & 7) ^ (kr1 & 7);
  const int vp = tid & 31, vdc = tid >> 5;

  for (int pass = 0; pass < 2; ++pass) {
    const int qt = pass ? qt0 : 15 - qt0;
    const int q0 = qt * 128;

    __syncthreads();  // prior pass fully done with Qs/Ks/VT before restage

    // ---- stage Q (1024 slots of 16B, chunk-XOR swizzle) ----
    #pragma unroll
    for (int p = 0; p < 4; ++p) {
      int s = tid + 256 * p;
      int r = s >> 3, cp = s & 7, c = cp ^ (r & 7);
      gld_lds16(qkv + base + (size_t)(q0 + r) * 3072 + qcol + c * 8, Qs + s * 8);
    }
    // prologue: issue K-DMA(0) + V(0) register loads (overlap with Q drain)
    gld_lds16(qkv + base + (size_t)(0 + kr0) * 3072 + kcol + kc0 * 8, Ks[0] + ks0 * 8);
    gld_lds16(qkv + base + (size_t)(0 + kr1) * 3072 + kcol + kc1 * 8, Ks[0] + ks1 * 8);
    uint4 vu0, vu1;
    {
      const unsigned short* vsrc = qkv + base + (size_t)(2 * vp) * 3072 + vcol + vdc * 8;
      vu0 = *(const uint4*)vsrc;
      vu1 = *(const uint4*)(vsrc + 3072);
    }
    __syncthreads();  // Qs + Ks[0] staged (V regs in flight or done)

    // ---- preload Q A-frags ----
    short8 qa[2][2];
    #pragma unroll
    for (int i = 0; i < 2; ++i)
      #pragma unroll
      for (int ks = 0; ks < 2; ++ks) {
        int ra = wv * 32 + i * 16 + l15;
        int cp = (ks * 4 + quad) ^ (ra & 7);
        qa[i][ks] = *(const short8*)(Qs + (ra * 8 + cp) * 8);
      }

    { // write VT[0] from V(0) regs
      unsigned short* dst = VT[0] + (size_t)(vdc * 8) * 72 + 2 * vp;
      *(unsigned int*)(dst + 0 * 72) = (vu0.x & 0xffffu) | (vu1.x << 16);
      *(unsigned int*)(dst + 1 * 72) = (vu0.x >> 16)     | (vu1.x & 0xffff0000u);
      *(unsigned int*)(dst + 2 * 72) = (vu0.y & 0xffffu) | (vu1.y << 16);
      *(unsigned int*)(dst + 3 * 72) = (vu0.y >> 16)     | (vu1.y & 0xffff0000u);
      *(unsigned int*)(dst + 4 * 72) = (vu0.z & 0xffffu) | (vu1.z << 16);
      *(unsigned int*)(dst + 5 * 72) = (vu0.z >> 16)     | (vu1.z & 0xffff0000u);
      *(unsigned int*)(dst + 6 * 72) = (vu0.w & 0xffffu) | (vu1.w << 16);
      *(unsigned int*)(dst + 7 * 72) = (vu0.w >> 16)     | (vu1.w & 0xffff0000u);
    }
    __syncthreads();  // Ks[0] + VT[0] visible

    floatx4 oacc[4][2];
    #pragma unroll
    for (int dt = 0; dt < 4; ++dt)
      #pragma unroll
      for (int q2 = 0; q2 < 2; ++q2)
        oacc[dt][q2] = (floatx4){0.f, 0.f, 0.f, 0.f};
    float m_i[2][4], l_i[2][4];
    #pragma unroll
    for (int i = 0; i < 2; ++i)
      #pragma unroll
      for (int r = 0; r < 4; ++r) { m_i[i][r] = -3.0e38f; l_i[i][r] = 0.0f; }

    const int nkt = 2 * qt + 2;
    for (int kt = 0; kt < nkt; ++kt) {
      const int k0 = kt * 64;
      const int cur = kt & 1, nxt = 1 - cur;
      const bool more = (kt + 1 < nkt);

      // ---- issue next tile's loads FIRST (overlap with compute below) ----
      if (more) {
        const int kn = k0 + 64;
        gld_lds16(qkv + base + (size_t)(kn + kr0) * 3072 + kcol + kc0 * 8, Ks[nxt] + ks0 * 8);
        gld_lds16(qkv + base + (size_t)(kn + kr1) * 3072 + kcol + kc1 * 8, Ks[nxt] + ks1 * 8);
        const unsigned short* vsrc = qkv + base + (size_t)(kn + 2 * vp) * 3072 + vcol + vdc * 8;
        vu0 = *(const uint4*)vsrc;
        vu1 = *(const uint4*)(vsrc + 3072);
      }

      // ---- S = Q K^T on Ks[cur] ----
      short8 kb[4][2];
      #pragma unroll
      for (int j = 0; j < 4; ++j)
        #pragma unroll
        for (int ks = 0; ks < 2; ++ks) {
          int rb = j * 16 + l15;
          int cp = (ks * 4 + quad) ^ (rb & 7);
          kb[j][ks] = *(const short8*)(Ks[cur] + (rb * 8 + cp) * 8);
        }
      floatx4 s_[2][4];
      #pragma unroll
      for (int i = 0; i < 2; ++i)
        #pragma unroll
        for (int j = 0; j < 4; ++j)
          s_[i][j] = (floatx4){0.f, 0.f, 0.f, 0.f};
      #pragma unroll
      for (int i = 0; i < 2; ++i)
        #pragma unroll
        for (int j = 0; j < 4; ++j)
          #pragma unroll
          for (int ks = 0; ks < 2; ++ks)
            s_[i][j] = __builtin_amdgcn_mfma_f32_16x16x32_bf16(qa[i][ks], kb[j][ks], s_[i][j], 0, 0, 0);

      // ---- mask + online softmax (registers) + P write ----
      #pragma unroll
      for (int i = 0; i < 2; ++i) {
        const int rowmin = q0 + wv * 32 + i * 16;
        const int rowb = rowmin + quad * 4;
        if (k0 + 63 > rowmin) {
          #pragma unroll
          for (int j = 0; j < 4; ++j) {
            const int col = k0 + j * 16 + l15;
            #pragma unroll
            for (int r = 0; r < 4; ++r)
              if (col > rowb + r) s_[i][j][r] = -3.0e38f;
          }
        }
        float fm[4], al[4], rs[4];
        #pragma unroll
        for (int r = 0; r < 4; ++r)
          fm[r] = fmaxf(fmaxf(s_[i][0][r], s_[i][1][r]), fmaxf(s_[i][2][r], s_[i][3][r]));
        #pragma unroll
        for (int msk = 1; msk < 16; msk <<= 1)
          #pragma unroll
          for (int r = 0; r < 4; ++r)
            fm[r] = fmaxf(fm[r], __shfl_xor(fm[r], msk, 64));
        #pragma unroll
        for (int r = 0; r < 4; ++r) {
          const float mn = fmaxf(m_i[i][r], fm[r]);
          al[r] = __expf(m_i[i][r] - mn);
          m_i[i][r] = mn;
        }
        #pragma unroll
        for (int j = 0; j < 4; ++j)
          #pragma unroll
          for (int r = 0; r < 4; ++r)
            s_[i][j][r] = __expf(s_[i][j][r] - m_i[i][r]);
        #pragma unroll
        for (int r = 0; r < 4; ++r)
          rs[r] = (s_[i][0][r] + s_[i][1][r]) + (s_[i][2][r] + s_[i][3][r]);
        #pragma unroll
        for (int msk = 1; msk < 16; msk <<= 1)
          #pragma unroll
          for (int r = 0; r < 4; ++r)
            rs[r] += __shfl_xor(rs[r], msk, 64);
        #pragma unroll
        for (int r = 0; r < 4; ++r)
          l_i[i][r] = l_i[i][r] * al[r] + rs[r];
        if (l15 == 0) {
          float4 a4 = { al[0], al[1], al[2], al[3] };
          *(float4*)(stat_s + wv * 32 + i * 16 + quad * 4) = a4;
        }
        #pragma unroll
        for (int j = 0; j < 4; ++j)
          #pragma unroll
          for (int r = 0; r < 4; ++r)
            Ps[(size_t)(wv * 32 + i * 16 + quad * 4 + r) * 72 + j * 16 + l15] = f2bits(s_[i][j][r]);
      }

      // ---- O^T += V^T P^T on VT[cur] (wave-local; no barrier) ----
      float alq[2];
      #pragma unroll
      for (int q2 = 0; q2 < 2; ++q2)
        alq[q2] = stat_s[wv * 32 + q2 * 16 + l15];
      #pragma unroll
      for (int dt = 0; dt < 4; ++dt)
        #pragma unroll
        for (int q2 = 0; q2 < 2; ++q2)
          #pragma unroll
          for (int r = 0; r < 4; ++r)
            oacc[dt][q2][r] *= alq[q2];

      short8 va[4][2], pb[2][2];
      #pragma unroll
      for (int dt = 0; dt < 4; ++dt)
        #pragma unroll
        for (int ks = 0; ks < 2; ++ks)
          va[dt][ks] = *(const short8*)(VT[cur] + (size_t)(dt * 16 + l15) * 72 + ks * 32 + quad * 8);
      #pragma unroll
      for (int q2 = 0; q2 < 2; ++q2)
        #pragma unroll
        for (int ks = 0; ks < 2; ++ks)
          pb[q2][ks] = *(const short8*)(Ps + (size_t)(wv * 32 + q2 * 16 + l15) * 72 + ks * 32 + quad * 8);
      #pragma unroll
      for (int dt = 0; dt < 4; ++dt)
        #pragma unroll
        for (int q2 = 0; q2 < 2; ++q2)
          #pragma unroll
          for (int ks = 0; ks < 2; ++ks)
            oacc[dt][q2] = __builtin_amdgcn_mfma_f32_16x16x32_bf16(va[dt][ks], pb[q2][ks], oacc[dt][q2], 0, 0, 0);

      // ---- publish next buffers ----
      if (more) {
        __syncthreads();  // drains K-DMA(nxt) (overlapped); VT[nxt] readers done
        unsigned short* dst = VT[nxt] + (size_t)(vdc * 8) * 72 + 2 * vp;
        *(unsigned int*)(dst + 0 * 72) = (vu0.x & 0xffffu) | (vu1.x << 16);
        *(unsigned int*)(dst + 1 * 72) = (vu0.x >> 16)     | (vu1.x & 0xffff0000u);
        *(unsigned int*)(dst + 2 * 72) = (vu0.y & 0xffffu) | (vu1.y << 16);
        *(unsigned int*)(dst + 3 * 72) = (vu0.y >> 16)     | (vu1.y & 0xffff0000u);
        *(unsigned int*)(dst + 4 * 72) = (vu0.z & 0xffffu) | (vu1.z << 16);
        *(unsigned int*)(dst + 5 * 72) = (vu0.z >> 16)     | (vu1.z & 0xffff0000u);
        *(unsigned int*)(dst + 6 * 72) = (vu0.w & 0xffffu) | (vu1.w << 16);
        *(unsigned int*)(dst + 7 * 72) = (vu0.w >> 16)     | (vu1.w & 0xffff0000u);
        __syncthreads();  // Ks[nxt] + VT[nxt] visible for next iter
      }
    }

    // ---- epilogue: O = O^T / l * 32^-1 ----
    if (l15 == 0) {
      #pragma unroll
      for (int i = 0; i < 2; ++i) {
        float4 l4 = { l_i[i][0], l_i[i][1], l_i[i][2], l_i[i][3] };
        *(float4*)(stat_s + wv * 32 + i * 16 + quad * 4) = l4;
      }
    }
    #pragma unroll
    for (int q2 = 0; q2 < 2; ++q2) {
      const float linv = 0.03125f / stat_s[wv * 32 + q2 * 16 + l15];
      const size_t row = (size_t)b * 2048 + q0 + wv * 32 + q2 * 16 + l15;
      #pragma unroll
      for (int dt = 0; dt < 4; ++dt) {
        const int col = h * 64 + dt * 16 + quad * 4;
        ushort4 o4 = { f2bits(oacc[dt][q2][0] * linv), f2bits(oacc[dt][q2][1] * linv),
                       f2bits(oacc[dt][q2][2] * linv), f2bits(oacc[dt][q2][3] * linv) };
        *(ushort4*)(o + row * 1024 + col) = o4;
      }
    }
  }
}

extern "C" void kernel_launch(void* const* d_in, const int* in_sizes, int n_in,
                              void* d_out, int out_size, void* d_ws, size_t ws_size,
                              hipStream_t stream)
{
  (void)in_sizes; (void)n_in; (void)out_size; (void)ws_size;
  const float* x      = (const float*)d_in[0];
  const float* w_attn = (const float*)d_in[1];
  const float* b_attn = (const float*)d_in[2];
  const float* w_proj = (const float*)d_in[3];
  const float* b_proj = (const float*)d_in[4];
  const float* w_fc1  = (const float*)d_in[5];
  const float* b_fc1  = (const float*)d_in[6];
  const float* w_fc2  = (const float*)d_in[7];
  const float* b_fc2  = (const float*)d_in[8];
  const float* g1     = (const float*)d_in[9];
  const float* g2     = (const float*)d_in[10];
  float* out = (float*)d_out;

  // ws layout (88 MB): h/ov bf16 @0 (8MB), qkv bf16 @8MB (24MB, h2 reuses 8..16MB),
  //                    x1 f32 @32MB (16MB), h3 bf16 @48MB (32MB), WT scratch @80MB (8MB)
  char* ws = (char*)d_ws;
  unsigned short* h   = (unsigned short*)(ws);
  unsigned short* qkv = (unsigned short*)(ws + ((size_t)8  << 20));
  unsigned short* ov  = (unsigned short*)(ws);                       // reuse h
  float*          x1  = (float*)         (ws + ((size_t)32 << 20));
  unsigned short* h2  = (unsigned short*)(ws + ((size_t)8  << 20));  // reuse qkv
  unsigned short* h3  = (unsigned short*)(ws + ((size_t)48 << 20));
  unsigned short* WT  = (unsigned short*)(ws + ((size_t)80 << 20));

  const int M = 4096;

  rmsnorm_r9<<<M, 256, 0, stream>>>(x, g1, h);
  wprep_r9<<<dim3(3072 / 32, 1024 / 32), 256, 0, stream>>>(w_attn, WT, 1024, 3072);
  gemm_r9<0><<<dim3(3072 / 128, M / 128), 256, 0, stream>>>(h, WT, b_attn, nullptr, qkv, M, 3072, 1024);
  attn_r9<<<dim3(8, 32), 256, 0, stream>>>(qkv, ov);
  wprep_r9<<<dim3(1024 / 32, 1024 / 32), 256, 0, stream>>>(w_proj, WT, 1024, 1024);
  gemm_r9<1><<<dim3(1024 / 128, M / 128), 256, 0, stream>>>(ov, WT, b_proj, x, x1, M, 1024, 1024);
  rmsnorm_r9<<<M, 256, 0, stream>>>(x1, g2, h2);
  wprep_r9<<<dim3(4096 / 32, 1024 / 32), 256, 0, stream>>>(w_fc1, WT, 1024, 4096);
  gemm_r9<2><<<dim3(4096 / 128, M / 128), 256, 0, stream>>>(h2, WT, b_fc1, nullptr, h3, M, 4096, 1024);
  wprep_r9<<<dim3(1024 / 32, 4096 / 32), 256, 0, stream>>>(w_fc2, WT, 4096, 1024);
  gemm_r9<3><<<dim3(1024 / 128, M / 128), 256, 0, stream>>>(h3, WT, b_fc2, x1, out, M, 1024, 4096);
}